// Round 1
// baseline (1419.786 us; speedup 1.0000x reference)
//
#include <hip/hip_runtime.h>

// Monotonic unsigned key for float ordering (handles mixed signs):
//   f >= 0: key = bits | 0x80000000   (so +0 -> 0x80000000, +inf -> 0xFF800000)
//   f <  0: key = ~bits               (so -0 -> 0x7FFFFFFF, -inf -> 0x007FFFFF)
#define KEY_NEG_INF 0x007FFFFFu

__device__ __forceinline__ unsigned f2key(float f) {
    unsigned b = __float_as_uint(f);
    return (b & 0x80000000u) ? ~b : (b | 0x80000000u);
}
__device__ __forceinline__ float key2f(unsigned k) {
    unsigned b = (k & 0x80000000u) ? (k ^ 0x80000000u) : ~k;
    return __uint_as_float(b);
}

// Output layout per node n (256 floats):
//   [  0.. 63] sum accumulator          -> final: sum
//   [ 64..127] sumsq accumulator        -> final: mean
//   [128..191] max-key accumulator      -> final: max (0 if empty)
//   [192..255] slot 192 = degree count  -> final: std
__global__ void init_out(float* __restrict__ out, long long total) {
    long long i = blockIdx.x * 256LL + threadIdx.x;
    if (i >= total) return;
    int c = (int)(i & 255);
    float v = (c >= 128 && c < 192) ? __uint_as_float(KEY_NEG_INF) : 0.0f;
    out[i] = v;
}

__global__ void scatter(const float* __restrict__ msg, const int* __restrict__ dst,
                        int idx_stride, float* __restrict__ out, long long total) {
    long long i = blockIdx.x * 256LL + threadIdx.x;
    if (i >= total) return;
    long long e = i >> 6;       // edge index: one 64-lane wave per edge
    int d = (int)(i & 63);      // feature index = lane
    int n = dst[e * idx_stride];   // wave-uniform broadcast load
    float v = msg[i];              // coalesced 256B row per wave
    float* base = out + (long long)n * 256 + d;
    atomicAdd(base, v);                                  // sum
    atomicAdd(base + 64, v * v);                         // sum of squares
    atomicMax((unsigned*)(base + 128), f2key(v));        // max via key
    if (d == 0) atomicAdd(base + 192, 1.0f);             // degree (exact in fp32 for deg < 2^24)
}

__global__ void finalize(float* __restrict__ out, int N) {
    int i = blockIdx.x * 256 + threadIdx.x;
    if (i >= N * 64) return;
    int n = i >> 6;             // one wave per node
    int d = i & 63;
    float* base = out + (long long)n * 256;
    float s   = base[d];
    float sq  = base[64 + d];
    unsigned k = __float_as_uint(base[128 + d]);
    float cnt = base[192];      // wave-uniform broadcast; read BEFORE lane 0's store below
    float deg = fmaxf(cnt, 1.0f);
    float mean = s / deg;
    float var  = fmaxf(sq / deg - mean * mean, 0.0f);
    float mx   = (k == KEY_NEG_INF) ? 0.0f : key2f(k);
    base[64 + d]  = mean;
    base[128 + d] = mx;
    base[192 + d] = sqrtf(var + 1e-8f);
}

extern "C" void kernel_launch(void* const* d_in, const int* in_sizes, int n_in,
                              void* d_out, int out_size, void* d_ws, size_t ws_size,
                              hipStream_t stream) {
    const float* msg = (const float*)d_in[0];
    const int*   dst = (const int*)d_in[1];
    float* out = (float*)d_out;

    long long E = (long long)in_sizes[0] / 64;   // 1,600,000
    int N = out_size / 256;                      // 100,000
    // Defensive: if dst was materialized as int64, in_sizes[1] counts 2x int32 words.
    int idx_stride = ((long long)in_sizes[1] == 2 * E) ? 2 : 1;

    long long init_total = (long long)N * 256;
    init_out<<<(unsigned)((init_total + 255) / 256), 256, 0, stream>>>(out, init_total);

    long long scat_total = E * 64;
    scatter<<<(unsigned)((scat_total + 255) / 256), 256, 0, stream>>>(msg, dst, idx_stride, out, scat_total);

    finalize<<<(unsigned)(((long long)N * 64 + 255) / 256), 256, 0, stream>>>(out, N);
}

// Round 2
// 837.459 us; speedup vs baseline: 1.6954x; 1.6954x over previous
//
#include <hip/hip_runtime.h>
#include <float.h>

// ---------------- counting-sort + gather-reduce multi-aggregation ----------------
// ws layout (ints): counts[N] | offsets[N+1] | cursor[N] | partials[512] | perm[E]

__global__ void zero_counts(int* __restrict__ counts, int N) {
    int i = blockIdx.x * 256 + threadIdx.x;
    if (i < N) counts[i] = 0;
}

__global__ void hist(const int* __restrict__ dst, int stride, int* __restrict__ counts, int E) {
    int e = blockIdx.x * 256 + threadIdx.x;
    if (e < E) atomicAdd(&counts[dst[(long long)e * stride]], 1);
}

// Per-block exclusive scan; writes block-local exclusive values + block totals.
__global__ void scan1(const int* __restrict__ counts, int* __restrict__ offsets,
                      int* __restrict__ partials, int N) {
    __shared__ int s[256];
    int t = threadIdx.x;
    int i = blockIdx.x * 256 + t;
    int x = (i < N) ? counts[i] : 0;
    s[t] = x;
    __syncthreads();
    for (int o = 1; o < 256; o <<= 1) {
        int y = (t >= o) ? s[t - o] : 0;
        __syncthreads();
        s[t] += y;
        __syncthreads();
    }
    if (i < N) offsets[i] = s[t] - x;          // exclusive within block
    if (t == 255) partials[blockIdx.x] = s[255];
}

// Single-block exclusive scan of up to 512 partials.
__global__ void scan2(int* __restrict__ partials, int NB) {
    __shared__ int s[512];
    int t = threadIdx.x;
    int x = (t < NB) ? partials[t] : 0;
    s[t] = x;
    __syncthreads();
    for (int o = 1; o < 512; o <<= 1) {
        int y = (t >= o) ? s[t - o] : 0;
        __syncthreads();
        s[t] += y;
        __syncthreads();
    }
    if (t < NB) partials[t] = s[t] - x;        // exclusive
}

__global__ void scan3(int* __restrict__ offsets, const int* __restrict__ partials,
                      int* __restrict__ cursor, int N, int E) {
    int i = blockIdx.x * 256 + threadIdx.x;
    if (i < N) {
        int off = offsets[i] + partials[blockIdx.x];
        offsets[i] = off;
        cursor[i] = off;
    }
    if (i == 0) offsets[N] = E;
}

__global__ void permscatter(const int* __restrict__ dst, int stride,
                            int* __restrict__ cursor, int* __restrict__ perm, int E) {
    int e = blockIdx.x * 256 + threadIdx.x;
    if (e < E) {
        int n = dst[(long long)e * stride];
        int pos = atomicAdd(&cursor[n], 1);
        perm[pos] = e;
    }
}

// One wave per node; lane = feature. Registers-only accumulation, single write.
__global__ void reduce(const float* __restrict__ msg, const int* __restrict__ perm,
                       const int* __restrict__ offsets, float* __restrict__ out, int N) {
    int node = blockIdx.x * 4 + (threadIdx.x >> 6);
    if (node >= N) return;
    int d = threadIdx.x & 63;
    int beg = offsets[node];
    int end = offsets[node + 1];

    float s = 0.0f, sq = 0.0f, mx = -FLT_MAX;
    int eid_next = (beg < end) ? perm[beg] : 0;
    for (int i = beg; i < end; ++i) {
        int eid = eid_next;
        if (i + 1 < end) eid_next = perm[i + 1];   // prefetch next edge id
        float v = msg[(long long)eid * 64 + d];    // coalesced 256B row per wave
        s += v;
        sq += v * v;
        mx = fmaxf(mx, v);
    }
    float deg = fmaxf((float)(end - beg), 1.0f);
    float mean = s / deg;
    float var  = fmaxf(sq / deg - mean * mean, 0.0f);
    float mxo  = (end > beg) ? mx : 0.0f;          // empty segment -> 0 (matches isfinite replace)

    float* base = out + (long long)node * 256;
    base[d]       = s;
    base[64 + d]  = mean;
    base[128 + d] = mxo;
    base[192 + d] = sqrtf(var + 1e-8f);
}

extern "C" void kernel_launch(void* const* d_in, const int* in_sizes, int n_in,
                              void* d_out, int out_size, void* d_ws, size_t ws_size,
                              hipStream_t stream) {
    const float* msg = (const float*)d_in[0];
    const int*   dst = (const int*)d_in[1];
    float* out = (float*)d_out;

    int E = in_sizes[0] / 64;                 // 1,600,000
    int N = out_size / 256;                   // 100,000
    int stride = (in_sizes[1] == 2 * E) ? 2 : 1;   // int64-as-int32-pairs defense

    int* counts   = (int*)d_ws;
    int* offsets  = counts + N;               // N+1
    int* cursor   = offsets + N + 1;
    int* partials = cursor + N;               // 512
    int* perm     = partials + 512;           // E

    int NB_N = (N + 255) / 256;               // 391 (<= 512 required for scan2)
    int NB_E = (E + 255) / 256;

    zero_counts<<<NB_N, 256, 0, stream>>>(counts, N);
    hist<<<NB_E, 256, 0, stream>>>(dst, stride, counts, E);
    scan1<<<NB_N, 256, 0, stream>>>(counts, offsets, partials, N);
    scan2<<<1, 512, 0, stream>>>(partials, NB_N);
    scan3<<<NB_N, 256, 0, stream>>>(offsets, partials, cursor, N, E);
    permscatter<<<NB_E, 256, 0, stream>>>(dst, stride, cursor, perm, E);
    reduce<<<(N + 3) / 4, 256, 0, stream>>>(msg, perm, offsets, out, N);
}